// Round 1
// baseline (249.290 us; speedup 1.0000x reference)
//
#include <hip/hip_runtime.h>
#include <math.h>

#define NB 4
#define NL 256
#define ND 512
#define NH 8
#define NR 64
#define NDK 64

// ---------------------------------------------------------------------------
// Kernel 1: QKV projection.  q/k/v = x @ W^T + b, stored as [B,H,L,DK].
// 64x64 output tiles, 256 threads, 4x4 micro-tile, K-tiles of 16.
// ---------------------------------------------------------------------------
__global__ __launch_bounds__(256)
void qkv_proj_kernel(const float* __restrict__ Xq, const float* __restrict__ Xk,
                     const float* __restrict__ Xv,
                     const float* __restrict__ Wq, const float* __restrict__ bq,
                     const float* __restrict__ Wk, const float* __restrict__ bk,
                     const float* __restrict__ Wv, const float* __restrict__ bv,
                     float* __restrict__ Oq, float* __restrict__ Ok,
                     float* __restrict__ Ov)
{
    const int z = blockIdx.z;
    const float* __restrict__ X    = (z == 0) ? Xq : ((z == 1) ? Xk : Xv);
    const float* __restrict__ W    = (z == 0) ? Wq : ((z == 1) ? Wk : Wv);
    const float* __restrict__ bias = (z == 0) ? bq : ((z == 1) ? bk : bv);
    float* __restrict__ Out        = (z == 0) ? Oq : ((z == 1) ? Ok : Ov);

    __shared__ float As[64][17];
    __shared__ float Bs[64][17];

    const int t  = threadIdx.x;
    const int lr = t >> 2;            // load row 0..63
    const int lk = (t & 3) << 2;      // load k-offset {0,4,8,12}
    const int ty = t >> 4;            // 0..15
    const int tx = t & 15;            // 0..15

    const int row0 = blockIdx.x * 64; // over M = B*L = 1024
    const int col0 = blockIdx.y * 64; // over N = 512

    float acc[4][4] = {{0.f,0.f,0.f,0.f},{0.f,0.f,0.f,0.f},
                       {0.f,0.f,0.f,0.f},{0.f,0.f,0.f,0.f}};

    for (int kt = 0; kt < ND; kt += 16) {
        float4 a4 = *(const float4*)&X[(size_t)(row0 + lr) * ND + kt + lk];
        float4 b4 = *(const float4*)&W[(size_t)(col0 + lr) * ND + kt + lk];
        As[lr][lk+0] = a4.x; As[lr][lk+1] = a4.y; As[lr][lk+2] = a4.z; As[lr][lk+3] = a4.w;
        Bs[lr][lk+0] = b4.x; Bs[lr][lk+1] = b4.y; Bs[lr][lk+2] = b4.z; Bs[lr][lk+3] = b4.w;
        __syncthreads();
        #pragma unroll
        for (int kk = 0; kk < 16; ++kk) {
            float a[4], b[4];
            #pragma unroll
            for (int i = 0; i < 4; ++i) a[i] = As[ty*4 + i][kk];
            #pragma unroll
            for (int j = 0; j < 4; ++j) b[j] = Bs[tx*4 + j][kk];
            #pragma unroll
            for (int i = 0; i < 4; ++i)
                #pragma unroll
                for (int j = 0; j < 4; ++j) acc[i][j] += a[i] * b[j];
        }
        __syncthreads();
    }

    const int h = blockIdx.y;   // N-tile == head (64 cols per head)
    float b0 = bias[col0 + tx*4 + 0];
    float b1 = bias[col0 + tx*4 + 1];
    float b2 = bias[col0 + tx*4 + 2];
    float b3 = bias[col0 + tx*4 + 3];
    #pragma unroll
    for (int i = 0; i < 4; ++i) {
        int r  = row0 + ty*4 + i;
        int bb = r >> 8;
        int ll = r & 255;
        float4 o;
        o.x = acc[i][0] + b0; o.y = acc[i][1] + b1;
        o.z = acc[i][2] + b2; o.w = acc[i][3] + b3;
        *(float4*)&Out[(((size_t)(bb*NH + h) * NL) + ll) * NDK + tx*4] = o;
    }
}

// ---------------------------------------------------------------------------
// Kernel 2: c2p = q . rel_k^T  and  p2c = k . rel_q^T   -> [B,H,L,R]
// Per block: one (b,h), one 64-row l-tile, full 64x64 output, K=64.
// ---------------------------------------------------------------------------
__global__ __launch_bounds__(256)
void rel_proj_kernel(const float* __restrict__ Q, const float* __restrict__ K,
                     const float* __restrict__ RelK, const float* __restrict__ RelQ,
                     float* __restrict__ C2P, float* __restrict__ P2C)
{
    const int z  = blockIdx.z;   // 0: c2p (q x rel_k), 1: p2c (k x rel_q)
    const int bh = blockIdx.y;
    const int h  = bh & 7;
    const int l0 = blockIdx.x * 64;

    const float* __restrict__ A  = ((z == 0) ? Q : K) + (size_t)bh * NL * NDK + (size_t)l0 * NDK;
    const float* __restrict__ Bm = ((z == 0) ? RelK : RelQ) + (size_t)h * NR * NDK;
    float* __restrict__ C        = ((z == 0) ? C2P : P2C) + (size_t)bh * NL * NR + (size_t)l0 * NR;

    __shared__ float As[64][17];
    __shared__ float Bs[64][17];

    const int t  = threadIdx.x;
    const int lr = t >> 2;
    const int lk = (t & 3) << 2;
    const int ty = t >> 4;
    const int tx = t & 15;

    float acc[4][4] = {{0.f,0.f,0.f,0.f},{0.f,0.f,0.f,0.f},
                       {0.f,0.f,0.f,0.f},{0.f,0.f,0.f,0.f}};

    for (int kt = 0; kt < NDK; kt += 16) {
        float4 a4 = *(const float4*)&A[(size_t)lr * NDK + kt + lk];
        float4 b4 = *(const float4*)&Bm[(size_t)lr * NDK + kt + lk];
        As[lr][lk+0] = a4.x; As[lr][lk+1] = a4.y; As[lr][lk+2] = a4.z; As[lr][lk+3] = a4.w;
        Bs[lr][lk+0] = b4.x; Bs[lr][lk+1] = b4.y; Bs[lr][lk+2] = b4.z; Bs[lr][lk+3] = b4.w;
        __syncthreads();
        #pragma unroll
        for (int kk = 0; kk < 16; ++kk) {
            float a[4], b[4];
            #pragma unroll
            for (int i = 0; i < 4; ++i) a[i] = As[ty*4 + i][kk];
            #pragma unroll
            for (int j = 0; j < 4; ++j) b[j] = Bs[tx*4 + j][kk];
            #pragma unroll
            for (int i = 0; i < 4; ++i)
                #pragma unroll
                for (int j = 0; j < 4; ++j) acc[i][j] += a[i] * b[j];
        }
        __syncthreads();
    }

    #pragma unroll
    for (int i = 0; i < 4; ++i) {
        float4 o;
        o.x = acc[i][0]; o.y = acc[i][1]; o.z = acc[i][2]; o.w = acc[i][3];
        *(float4*)&C[(size_t)(ty*4 + i) * NR + tx*4] = o;
    }
}

// ---------------------------------------------------------------------------
// Kernel 3: scores + gathers + scale + mask + softmax -> p [B,H,L,L]
// Block: (l-tile of 16, bh). 256 threads: i = t>>4 (row), j = t&15 (col lane).
// ---------------------------------------------------------------------------
__global__ __launch_bounds__(256)
void scores_softmax_kernel(const float* __restrict__ Q, const float* __restrict__ K,
                           const float* __restrict__ C2P, const float* __restrict__ P2C,
                           const int* __restrict__ RelPos, const void* __restrict__ MaskP,
                           float* __restrict__ Pout)
{
    const int bh = blockIdx.y;
    const int b  = bh >> 3;
    const int l0 = blockIdx.x * 16;
    const int t  = threadIdx.x;
    const int i  = t >> 4;
    const int j  = t & 15;

    __shared__ float qs[16][65];
    __shared__ float cs[16][65];
    __shared__ float ks[16][65];
    __shared__ float ps[16][65];
    __shared__ float sc[16][256];
    __shared__ int   rp[16][16];

    // ---- detect mask buffer layout (bool-u8 / f32 / i32), deterministic ----
    const unsigned char* mu = (const unsigned char*)MaskP;
    int loc1  = mu[t*4 + 1];
    int loc23 = mu[t*4 + 2] | mu[t*4 + 3];
    int any1  = __syncthreads_or(loc1);
    int any23 = __syncthreads_or(loc23);
    const int mlayout = any1 ? 0 : (any23 ? 1 : 2);  // 0=u8, 1=f32, 2=i32

    // ---- stage q rows and c2p rows for this l-tile ----
    {
        int row = t >> 4, d4 = (t & 15) << 2;
        float4 a = *(const float4*)&Q[((size_t)bh * NL + l0 + row) * NDK + d4];
        qs[row][d4+0] = a.x; qs[row][d4+1] = a.y; qs[row][d4+2] = a.z; qs[row][d4+3] = a.w;
        float4 c = *(const float4*)&C2P[((size_t)bh * NL + l0 + row) * NR + d4];
        cs[row][d4+0] = c.x; cs[row][d4+1] = c.y; cs[row][d4+2] = c.z; cs[row][d4+3] = c.w;
    }

    for (int mt = 0; mt < NL; mt += 16) {
        {
            int row = t >> 4, d4 = (t & 15) << 2;
            float4 kk4 = *(const float4*)&K[((size_t)bh * NL + mt + row) * NDK + d4];
            ks[row][d4+0] = kk4.x; ks[row][d4+1] = kk4.y; ks[row][d4+2] = kk4.z; ks[row][d4+3] = kk4.w;
            float4 pp4 = *(const float4*)&P2C[((size_t)bh * NL + mt + row) * NR + d4];
            ps[row][d4+0] = pp4.x; ps[row][d4+1] = pp4.y; ps[row][d4+2] = pp4.z; ps[row][d4+3] = pp4.w;
        }
        rp[i][j] = RelPos[((size_t)b * NL + l0 + i) * NL + mt + j];
        __syncthreads();

        float s = 0.f;
        #pragma unroll
        for (int d = 0; d < NDK; ++d) s += qs[i][d] * ks[j][d];
        int r = rp[i][j];
        s += cs[i][r] + ps[j][r];
        s *= (1.0f / 24.0f);   // 1 / (3 * sqrt(64))

        int mg = b * NL + mt + j;
        float mval;
        if (mlayout == 0)      mval = (float)mu[mg];
        else if (mlayout == 1) mval = ((const float*)MaskP)[mg];
        else                   mval = (float)((const int*)MaskP)[mg];
        if (mval != 0.0f) s = -1e9f;

        sc[i][mt + j] = s;
        __syncthreads();
    }

    // ---- softmax: row i handled by its 16 lanes j ----
    float mx = -INFINITY;
    #pragma unroll
    for (int s16 = 0; s16 < 16; ++s16) mx = fmaxf(mx, sc[i][j + 16*s16]);
    #pragma unroll
    for (int off = 8; off >= 1; off >>= 1) mx = fmaxf(mx, __shfl_xor(mx, off, 16));

    float sum = 0.f;
    #pragma unroll
    for (int s16 = 0; s16 < 16; ++s16) {
        float e = __expf(sc[i][j + 16*s16] - mx);
        sc[i][j + 16*s16] = e;
        sum += e;
    }
    #pragma unroll
    for (int off = 8; off >= 1; off >>= 1) sum += __shfl_xor(sum, off, 16);
    float inv = 1.0f / sum;

    #pragma unroll
    for (int s16 = 0; s16 < 16; ++s16)
        Pout[((size_t)bh * NL + l0 + i) * NL + j + 16*s16] = sc[i][j + 16*s16] * inv;
}

// ---------------------------------------------------------------------------
// Kernel 4: ctx[b,h,l,d] = sum_m p[b,h,l,m] * (v[b,h,m,d] + rel_v[b,l,m,h*64+d])
// One block per (b,l); streams the 512 KB rel_v slice.  Output ctx [B*L, 512].
// ---------------------------------------------------------------------------
__global__ __launch_bounds__(256)
void ctx_kernel(const float* __restrict__ P, const float* __restrict__ V,
                const float* __restrict__ RV, float* __restrict__ CTX)
{
    const int bl = blockIdx.x;
    const int b  = bl >> 8;
    const int l  = bl & 255;
    const int t  = threadIdx.x;

    __shared__ float pw[8][256];
    __shared__ float red[128][4];

    #pragma unroll
    for (int h = 0; h < 8; ++h)
        pw[h][t] = P[(((size_t)(b*NH + h) * NL) + l) * NL + t];
    __syncthreads();

    const int c    = t & 127;    // float4-column 0..127 (head = c>>4)
    const int half = t >> 7;     // row parity
    const int hc   = c >> 4;
    const int dk4  = c & 15;

    const float4* rv4 = (const float4*)RV + (size_t)bl * NL * 128 + c;
    const float4* vv4 = (const float4*)V  + ((size_t)(b*NH + hc) * NL) * 16 + dk4;

    float4 acc = make_float4(0.f, 0.f, 0.f, 0.f);
    #pragma unroll 4
    for (int m = half; m < NL; m += 2) {
        float  w  = pw[hc][m];
        float4 rv = rv4[(size_t)m * 128];
        float4 vv = vv4[(size_t)m * 16];
        acc.x += w * (rv.x + vv.x);
        acc.y += w * (rv.y + vv.y);
        acc.z += w * (rv.z + vv.z);
        acc.w += w * (rv.w + vv.w);
    }

    if (half) { red[c][0] = acc.x; red[c][1] = acc.y; red[c][2] = acc.z; red[c][3] = acc.w; }
    __syncthreads();
    if (!half) {
        acc.x += red[c][0]; acc.y += red[c][1]; acc.z += red[c][2]; acc.w += red[c][3];
        *(float4*)&CTX[(size_t)bl * ND + c*4] = acc;
    }
}

// ---------------------------------------------------------------------------
// Kernel 5: out = ctx @ Wo^T + bo   (plain row-major [1024][512])
// ---------------------------------------------------------------------------
__global__ __launch_bounds__(256)
void out_proj_kernel(const float* __restrict__ A, const float* __restrict__ W,
                     const float* __restrict__ bias, float* __restrict__ C)
{
    __shared__ float As[64][17];
    __shared__ float Bs[64][17];

    const int t  = threadIdx.x;
    const int lr = t >> 2;
    const int lk = (t & 3) << 2;
    const int ty = t >> 4;
    const int tx = t & 15;

    const int row0 = blockIdx.x * 64;
    const int col0 = blockIdx.y * 64;

    float acc[4][4] = {{0.f,0.f,0.f,0.f},{0.f,0.f,0.f,0.f},
                       {0.f,0.f,0.f,0.f},{0.f,0.f,0.f,0.f}};

    for (int kt = 0; kt < ND; kt += 16) {
        float4 a4 = *(const float4*)&A[(size_t)(row0 + lr) * ND + kt + lk];
        float4 b4 = *(const float4*)&W[(size_t)(col0 + lr) * ND + kt + lk];
        As[lr][lk+0] = a4.x; As[lr][lk+1] = a4.y; As[lr][lk+2] = a4.z; As[lr][lk+3] = a4.w;
        Bs[lr][lk+0] = b4.x; Bs[lr][lk+1] = b4.y; Bs[lr][lk+2] = b4.z; Bs[lr][lk+3] = b4.w;
        __syncthreads();
        #pragma unroll
        for (int kk = 0; kk < 16; ++kk) {
            float a[4], b[4];
            #pragma unroll
            for (int i = 0; i < 4; ++i) a[i] = As[ty*4 + i][kk];
            #pragma unroll
            for (int j = 0; j < 4; ++j) b[j] = Bs[tx*4 + j][kk];
            #pragma unroll
            for (int i = 0; i < 4; ++i)
                #pragma unroll
                for (int j = 0; j < 4; ++j) acc[i][j] += a[i] * b[j];
        }
        __syncthreads();
    }

    float b0 = bias[col0 + tx*4 + 0];
    float b1 = bias[col0 + tx*4 + 1];
    float b2 = bias[col0 + tx*4 + 2];
    float b3 = bias[col0 + tx*4 + 3];
    #pragma unroll
    for (int i = 0; i < 4; ++i) {
        int r = row0 + ty*4 + i;
        float4 o;
        o.x = acc[i][0] + b0; o.y = acc[i][1] + b1;
        o.z = acc[i][2] + b2; o.w = acc[i][3] + b3;
        *(float4*)&C[(size_t)r * ND + col0 + tx*4] = o;
    }
}

// ---------------------------------------------------------------------------
extern "C" void kernel_launch(void* const* d_in, const int* in_sizes, int n_in,
                              void* d_out, int out_size, void* d_ws, size_t ws_size,
                              hipStream_t stream)
{
    const float* query   = (const float*)d_in[0];
    const float* key     = (const float*)d_in[1];
    const float* value   = (const float*)d_in[2];
    const void*  mask    = d_in[3];
    const int*   rel_pos = (const int*)d_in[4];
    const float* rel_q   = (const float*)d_in[5];
    const float* rel_k   = (const float*)d_in[6];
    const float* rel_v   = (const float*)d_in[7];
    const float* Wq = (const float*)d_in[8];
    const float* bq = (const float*)d_in[9];
    const float* Wk = (const float*)d_in[10];
    const float* bk = (const float*)d_in[11];
    const float* Wv = (const float*)d_in[12];
    const float* bv = (const float*)d_in[13];
    const float* Wo = (const float*)d_in[14];
    const float* bo = (const float*)d_in[15];

    float* ws   = (float*)d_ws;
    float* q_ws = ws;                     // B*H*L*DK = 524288
    float* k_ws = q_ws + 524288;
    float* v_ws = k_ws + 524288;
    float* c2p  = v_ws + 524288;          // B*H*L*R = 524288
    float* p2c  = c2p + 524288;
    float* p    = p2c + 524288;           // B*H*L*L = 2097152
    float* ctx  = p + 2097152;            // B*L*D   = 524288

    qkv_proj_kernel<<<dim3(16, 8, 3), 256, 0, stream>>>(
        query, key, value, Wq, bq, Wk, bk, Wv, bv, q_ws, k_ws, v_ws);

    rel_proj_kernel<<<dim3(4, 32, 2), 256, 0, stream>>>(
        q_ws, k_ws, rel_k, rel_q, c2p, p2c);

    scores_softmax_kernel<<<dim3(16, 32), 256, 0, stream>>>(
        q_ws, k_ws, c2p, p2c, rel_pos, mask, p);

    ctx_kernel<<<dim3(1024), 256, 0, stream>>>(p, v_ws, rel_v, ctx);

    out_proj_kernel<<<dim3(16, 8), 256, 0, stream>>>(ctx, Wo, bo, (float*)d_out);
}